// Round 4
// baseline (291.604 us; speedup 1.0000x reference)
//
#include <hip/hip_runtime.h>
#include <math.h>

#define SE_B   32
#define SE_C   256
#define SE_HID 16
#define SE_HW  4096   // 64*64
#define SE_HW4 1024   // float4 per (b,c) plane

typedef float f4v __attribute__((ext_vector_type(4)));

// Kernel 1: per-(b,c) plane mean. One 256-thread block per plane
// (block-per-plane geometry measured fastest across rounds 0-3).
// Caching loads on purpose: leaves x resident in the 256 MiB L3 so the
// scale pass re-reads it without HBM traffic.
__global__ __launch_bounds__(256) void se_mean_kernel(const float* __restrict__ x,
                                                      float* __restrict__ s) {
    const int plane = blockIdx.x;  // b*C + c
    const float4* xp = (const float4*)x + (size_t)plane * SE_HW4;
    const int tid = threadIdx.x;

    float sum = 0.f;
#pragma unroll
    for (int k = 0; k < 4; ++k) {
        float4 v = xp[tid + k * 256];
        sum += (v.x + v.y) + (v.z + v.w);
    }
#pragma unroll
    for (int off = 32; off > 0; off >>= 1) sum += __shfl_down(sum, off, 64);

    __shared__ float part[4];
    if ((tid & 63) == 0) part[tid >> 6] = sum;
    __syncthreads();
    if (tid == 0) {
        float tot = (part[0] + part[1]) + (part[2] + part[3]);
        s[plane] = tot * (1.0f / SE_HW);
    }
}

// Kernel 2: fused gate + scale, block-per-plane, ZERO barriers / ZERO LDS.
// Round 0's winning geometry (4 float4/thread, 8192 blocks) but the gate
// is computed per-wave with shuffles instead of the 3-barrier LDS chain,
// so the 4 in-flight x loads are never drained by an s_barrier's forced
// vmcnt(0) — the gate math (L1-resident s/w1 reads + ~80 VALU ops +
// 6 cross-lane ops) genuinely overlaps the x load latency.
//   lane (i = lane&15 hidden unit, j = lane>>4 chunk of 64 channels):
//   p   = sum_k s[b, j*64+k] * w1[i, j*64+k]
//   h_i = relu(b1_i + shfl_xor-sum over j)
//   g   = sigmoid(b2_c + shfl_xor-sum_i h_i * w2[c,i])
// NT stores keep the 128 MiB of output from evicting x in L3.
__global__ __launch_bounds__(256) void se_scale_kernel(const float* __restrict__ x,
                                                       const float* __restrict__ s,
                                                       const float* __restrict__ w1,
                                                       const float* __restrict__ b1,
                                                       const float* __restrict__ w2,
                                                       const float* __restrict__ b2,
                                                       float* __restrict__ out) {
    const int plane = blockIdx.x;
    const int b = plane >> 8;    // / SE_C
    const int c = plane & 255;   // % SE_C
    const int tid = threadIdx.x;
    const int lane = tid & 63;

    const float4* xp = (const float4*)x + (size_t)plane * SE_HW4;
    float4* op = (float4*)out + (size_t)plane * SE_HW4;

    // Issue the plane's x loads first; gate math overlaps their latency.
    float4 v0 = xp[tid];
    float4 v1 = xp[tid + 256];
    float4 v2 = xp[tid + 512];
    float4 v3 = xp[tid + 768];

    // Gate, in-wave (each of the 4 waves computes it redundantly).
    const int i = lane & 15;     // hidden unit
    const int j = lane >> 4;     // chunk of 64 channels
    const float4* srow = (const float4*)(s + b * SE_C) + j * 16;
    const float4* wrow = (const float4*)(w1 + i * SE_C) + j * 16;
    float p = 0.f;
#pragma unroll
    for (int k = 0; k < 16; ++k) {
        float4 sv = srow[k];
        float4 wv = wrow[k];
        p = fmaf(sv.x, wv.x, p);
        p = fmaf(sv.y, wv.y, p);
        p = fmaf(sv.z, wv.z, p);
        p = fmaf(sv.w, wv.w, p);
    }
    p += __shfl_xor(p, 16, 64);
    p += __shfl_xor(p, 32, 64);
    const float h = fmaxf(p + b1[i], 0.f);

    float t = h * w2[c * SE_HID + i];
#pragma unroll
    for (int off = 8; off > 0; off >>= 1) t += __shfl_xor(t, off, 64);
    const float gv = 1.0f / (1.0f + expf(-(t + b2[c])));

    v0.x *= gv; v0.y *= gv; v0.z *= gv; v0.w *= gv;
    v1.x *= gv; v1.y *= gv; v1.z *= gv; v1.w *= gv;
    v2.x *= gv; v2.y *= gv; v2.z *= gv; v2.w *= gv;
    v3.x *= gv; v3.y *= gv; v3.z *= gv; v3.w *= gv;

    __builtin_nontemporal_store(*(f4v*)&v0, (f4v*)(op + tid));
    __builtin_nontemporal_store(*(f4v*)&v1, (f4v*)(op + tid + 256));
    __builtin_nontemporal_store(*(f4v*)&v2, (f4v*)(op + tid + 512));
    __builtin_nontemporal_store(*(f4v*)&v3, (f4v*)(op + tid + 768));
}

extern "C" void kernel_launch(void* const* d_in, const int* in_sizes, int n_in,
                              void* d_out, int out_size, void* d_ws, size_t ws_size,
                              hipStream_t stream) {
    const float* x  = (const float*)d_in[0];
    const float* w1 = (const float*)d_in[1];
    const float* b1 = (const float*)d_in[2];
    const float* w2 = (const float*)d_in[3];
    const float* b2 = (const float*)d_in[4];
    float* out = (float*)d_out;

    float* s = (float*)d_ws;   // [B*C] plane means

    se_mean_kernel<<<SE_B * SE_C, 256, 0, stream>>>(x, s);
    se_scale_kernel<<<SE_B * SE_C, 256, 0, stream>>>(x, s, w1, b1, w2, b2, out);
}

// Round 5
// 250.973 us; speedup vs baseline: 1.1619x; 1.1619x over previous
//
#include <hip/hip_runtime.h>
#include <math.h>

#define SE_B   32
#define SE_C   256
#define SE_HID 16
#define SE_HW  4096   // 64*64
#define SE_HW4 1024   // float4 per (b,c) plane

// Kernel 1: per-(b,c) plane mean. One 256-thread block per plane
// (block-per-plane geometry measured fastest across rounds 0-4).
__global__ __launch_bounds__(256) void se_mean_kernel(const float* __restrict__ x,
                                                      float* __restrict__ s) {
    const int plane = blockIdx.x;  // b*C + c
    const float4* xp = (const float4*)x + (size_t)plane * SE_HW4;
    const int tid = threadIdx.x;

    float sum = 0.f;
#pragma unroll
    for (int k = 0; k < 4; ++k) {
        float4 v = xp[tid + k * 256];
        sum += (v.x + v.y) + (v.z + v.w);
    }
#pragma unroll
    for (int off = 32; off > 0; off >>= 1) sum += __shfl_down(sum, off, 64);

    __shared__ float part[4];
    if ((tid & 63) == 0) part[tid >> 6] = sum;
    __syncthreads();
    if (tid == 0) {
        float tot = (part[0] + part[1]) + (part[2] + part[3]);
        s[plane] = tot * (1.0f / SE_HW);
    }
}

// Kernel 2: fused gate + scale, block-per-plane.
// Round-4 post-mortem fixes:
//  - gate computed by WAVE 0 ONLY (shuffle reduction, no serial phases),
//    broadcast via one LDS float + a single __syncthreads. This cuts the
//    uncoalesced w1 line-traffic 4x vs round 4 (32768 -> 8192 gate evals)
//    and removes round 0's 3-barrier serial chain.
//  - NORMAL stores (not nontemporal): fills prove 6.7 TB/s with caching
//    stores; NT protected nothing (L3 is flushed by the harness poison
//    each iteration and x planes are read exactly once here).
// x loads are issued first; waves 1-3 carry them across the barrier while
// wave 0's gate math (L1-resident s/w1) overlaps their latency.
__global__ __launch_bounds__(256) void se_scale_kernel(const float* __restrict__ x,
                                                       const float* __restrict__ s,
                                                       const float* __restrict__ w1,
                                                       const float* __restrict__ b1,
                                                       const float* __restrict__ w2,
                                                       const float* __restrict__ b2,
                                                       float* __restrict__ out) {
    const int plane = blockIdx.x;
    const int b = plane >> 8;    // / SE_C
    const int c = plane & 255;   // % SE_C
    const int tid = threadIdx.x;
    const int lane = tid & 63;
    const int wave = tid >> 6;

    const float4* xp = (const float4*)x + (size_t)plane * SE_HW4;
    float4* op = (float4*)out + (size_t)plane * SE_HW4;

    // Issue the plane's x loads first; gate math overlaps their latency.
    float4 v0 = xp[tid];
    float4 v1 = xp[tid + 256];
    float4 v2 = xp[tid + 512];
    float4 v3 = xp[tid + 768];

    __shared__ float g_sh;
    if (wave == 0) {
        // lane (i = lane&15 hidden unit, j = lane>>4 chunk of 64 channels)
        const int i = lane & 15;
        const int j = lane >> 4;
        const float4* srow = (const float4*)(s + b * SE_C) + j * 16;
        const float4* wrow = (const float4*)(w1 + i * SE_C) + j * 16;
        float p = 0.f;
#pragma unroll
        for (int k = 0; k < 16; ++k) {
            float4 sv = srow[k];
            float4 wv = wrow[k];
            p = fmaf(sv.x, wv.x, p);
            p = fmaf(sv.y, wv.y, p);
            p = fmaf(sv.z, wv.z, p);
            p = fmaf(sv.w, wv.w, p);
        }
        p += __shfl_xor(p, 16, 64);
        p += __shfl_xor(p, 32, 64);
        const float h = fmaxf(p + b1[i], 0.f);

        float t = h * w2[c * SE_HID + i];
#pragma unroll
        for (int off = 8; off > 0; off >>= 1) t += __shfl_xor(t, off, 64);
        if (lane == 0) g_sh = 1.0f / (1.0f + expf(-(t + b2[c])));
    }
    __syncthreads();
    const float gv = g_sh;

    v0.x *= gv; v0.y *= gv; v0.z *= gv; v0.w *= gv;
    v1.x *= gv; v1.y *= gv; v1.z *= gv; v1.w *= gv;
    v2.x *= gv; v2.y *= gv; v2.z *= gv; v2.w *= gv;
    v3.x *= gv; v3.y *= gv; v3.z *= gv; v3.w *= gv;

    op[tid]       = v0;
    op[tid + 256] = v1;
    op[tid + 512] = v2;
    op[tid + 768] = v3;
}

extern "C" void kernel_launch(void* const* d_in, const int* in_sizes, int n_in,
                              void* d_out, int out_size, void* d_ws, size_t ws_size,
                              hipStream_t stream) {
    const float* x  = (const float*)d_in[0];
    const float* w1 = (const float*)d_in[1];
    const float* b1 = (const float*)d_in[2];
    const float* w2 = (const float*)d_in[3];
    const float* b2 = (const float*)d_in[4];
    float* out = (float*)d_out;

    float* s = (float*)d_ws;   // [B*C] plane means

    se_mean_kernel<<<SE_B * SE_C, 256, 0, stream>>>(x, s);
    se_scale_kernel<<<SE_B * SE_C, 256, 0, stream>>>(x, s, w1, b1, w2, b2, out);
}